// Round 9
// baseline (17723.796 us; speedup 1.0000x reference)
//
#include <hip/hip_runtime.h>
#include <cstdint>
#include <cstddef>

// LowRankRNN: h_{t+1} = h + coef*(-h + J@relu(h) + I_t),  J = G*W - B/N + M u v^T
//
// Persistent kernel, 64 blocks x 512 threads (1 block/CU), J in registers.
// Sync: sign-bit-encoded data IS the flag (x = relu(h) >= 0; x(t) stored with
// sign bit forced to phase enc(t)=(t>>1)&1; decode = clear sign bit; two
// buffers alternate by t&1 so stale data never satisfies a poll).
// Wave w polls only its chunk w (1 dwordx4/lane), decodes into LDS, one
// __syncthreads, all waves read x from LDS.
//
// R9 = R8 with ONE moved statement: the I_t prefetch is issued AFTER the
// __syncthreads, not before it.
//   __syncthreads on gfx950 = s_waitcnt vmcnt(0) lgkmcnt(0); s_barrier.
//   Since R3, the I_t prefetch (a fresh ~900cy HBM load) was issued between
//   poll-success and the barrier -> EVERY step's barrier drained it to
//   completion: a ~700-900cy bubble per step hiding inside the barrier.
//   Issued after the barrier, the load has the whole FMA+reduce+publish+
//   next-poll span to complete; the next vmcnt(0) it meets (next step's
//   poll) retires it for free (vmcnt completes in order; the poll load is
//   younger and slower). Bit-identical numerics; no protocol change.
//
// Overwrite safety unchanged: publishing x(t+2) requires having acquired all
// of x(t+1), which required every block's step-t barrier, i.e. all step-t
// reads of buffer t&1 are done before anyone can write it again. Per-dword
// store atomicity + per-word sign check handle partial arrival.

constexpr int   NN   = 2048;
constexpr int   TT   = 8192;
constexpr float COEF = 0.001f;             // DT/TAU
constexpr float G_   = 2.0f;
constexpr float BOFF = 10.0f / 2048.0f;    // B/N
constexpr float M_   = 1.5f;

constexpr int NBLK = 64;    // 1 block/CU
constexpr int TPB  = 512;   // 8 waves
constexpr int WPB  = TPB / 64;

typedef float f32x4 __attribute__((ext_vector_type(4)));
typedef int   i32x4 __attribute__((ext_vector_type(4)));

__device__ __forceinline__ i32x4 bc(const f32x4 x) { return __builtin_bit_cast(i32x4, x); }
__device__ __forceinline__ f32x4 fc(const i32x4 x) { return __builtin_bit_cast(f32x4, x); }

// buf0 polled first at t=2 expecting sign-SET  -> init sign-clear (waits)
// buf1 polled first at t=1 expecting sign-CLEAR -> init sign-set  (waits)
__global__ void init_xbufs(float* xb) {
  const int i = blockIdx.x * blockDim.x + threadIdx.x;   // 0..NN-1 over grid
  xb[i]      = 0.0f;
  xb[NN + i] = -1.0f;
}

// One DEVICE-scope 16B load + waitcnt inside one asm block (consumers are
// ordered by register dataflow; rule-#18 safe).
__device__ __forceinline__ f32x4 poll1(const float* p) {
  f32x4 c;
  asm volatile("global_load_dwordx4 %0, %1, off sc1\n\t"
               "s_waitcnt vmcnt(0)"
               : "=&v"(c) : "v"(p) : "memory");
  return c;
}

// DEVICE-scope write-through 16B publish store (visible at the device
// coherence point; per-dword atomicity)
__device__ __forceinline__ void store_wt(float* p, f32x4 v) {
  asm volatile("global_store_dwordx4 %0, %1, off sc1"
               :: "v"(p), "v"(v) : "memory");
}

// butterfly helpers — value-identical to p += __shfl_xor(p, m)
template <int CTRL>
__device__ __forceinline__ float xadd_dpp(float v) {
  const int t = __builtin_amdgcn_update_dpp(0, __builtin_bit_cast(int, v),
                                            CTRL, 0xF, 0xF, false);
  return v + __builtin_bit_cast(float, t);
}
template <int PAT>
__device__ __forceinline__ float xadd_swz(float v) {
  const int t = __builtin_amdgcn_ds_swizzle(__builtin_bit_cast(int, v), PAT);
  return v + __builtin_bit_cast(float, t);
}

__global__ __launch_bounds__(TPB, 2)
void rnn_persist(const float* __restrict__ I_t,
                 const float* __restrict__ h0,
                 const float* __restrict__ W,
                 const float* __restrict__ u,
                 const float* __restrict__ v,
                 float* __restrict__ out_h,   // d_out + TT, [TT][NN]
                 float* __restrict__ xbuf)    // 2*NN floats
{
  __shared__ f32x4 xs[2][NN / 4];             // 16 KB, double-buffered x

  const int tid = threadIdx.x;
  const int l   = tid & 63;
  const int w   = tid >> 6;
  const int gw  = blockIdx.x * WPB + w;           // global wave 0..511
  const int rb  = gw * 4;                         // this wave's 4 rows
  const int cb  = l * 4;                          // column base per 256-chunk

  // ---- J rows rb..rb+3: J[j][k] <-> row rb+j, cols k*256 + 4l
  f32x4 J[4][8];
#pragma unroll
  for (int j = 0; j < 4; ++j) {
    const float mu = M_ * u[rb + j];
#pragma unroll
    for (int k = 0; k < 8; ++k) {
      const int c = k * 256 + cb;
      const f32x4 wv = *(const f32x4*)(W + (size_t)(rb + j) * NN + c);
      const f32x4 vv = *(const f32x4*)(v + c);
      J[j][k] = G_ * wv - BOFF + mu * vv;
    }
  }

  float h[4];
#pragma unroll
  for (int j = 0; j < 4; ++j) h[j] = h0[rb + j];

  const f32x4 zero4 = {0.f, 0.f, 0.f, 0.f};

  // I_t pipeline: parity-selected regs; loads are issued AFTER each step's
  // barrier so no vmcnt(0) drain point ever waits on a fresh HBM load.
  f32x4 iva = *(const f32x4*)(I_t + rb);              // row 0
  f32x4 ivb = *(const f32x4*)(I_t + (size_t)NN + rb); // row 1 (in flight)

  for (int t = 0; t < TT; ++t) {
    const f32x4 icur4 = (t & 1) ? ivb : iva;
    const int bsel = t & 1;

    // ---- acquire this wave's chunk w of x(t)
    f32x4 c;
    if (t == 0) {
      const f32x4 hv = *(const f32x4*)(h0 + w * 256 + cb);
      c = __builtin_elementwise_max(hv, zero4);   // x(0) = relu(h0)
    } else {
      const bool enc = ((t >> 1) & 1) != 0;       // x(t) stored sign-flipped?
      const float* pb = xbuf + bsel * NN + w * 256 + cb;
      unsigned spins = 0;
      if (enc) {
        for (;;) {  // fresh values have sign SET: all 4 words negative
          c = poll1(pb);
          const i32x4 b = bc(c);
          if (__all(((b.x & b.y) & (b.z & b.w)) < 0)) break;
          if (++spins > (1u << 22)) break;        // escape hatch; never hit
        }
      } else {
        for (;;) {  // fresh values have sign CLEAR: all 4 words non-negative
          c = poll1(pb);
          const i32x4 b = bc(c);
          if (__all(((b.x | b.y) | (b.z | b.w)) >= 0)) break;
          if (++spins > (1u << 22)) break;
        }
      }
      i32x4 b = bc(c);
      b &= 0x7fffffff;                            // exact decode: clear sign
      c = __builtin_bit_cast(f32x4, b);
    }

    xs[bsel][w * 64 + l] = c;                     // ds_write_b128
    __syncthreads();   // drains vmcnt/lgkmcnt — nothing fresh outstanding now

    // ---- issue I_t row t+2 HERE (post-barrier): ~2800cy until the next
    // vmcnt(0) (next step's poll), which retires it for free (in-order,
    // older than the poll load). Never drained by a barrier.
    if (t + 2 < TT) {
      const f32x4 nv = *(const f32x4*)(I_t + (size_t)(t + 2) * NN + rb);
      if (t & 1) ivb = nv; else iva = nv;
    }

    // ---- p = J @ x from LDS (values already relu'd + decoded)
    f32x4 p4[4] = {zero4, zero4, zero4, zero4};
#pragma unroll
    for (int k = 0; k < 8; ++k) {
      const f32x4 xv = xs[bsel][k * 64 + l];      // ds_read_b128, conflict-free
#pragma unroll
      for (int j = 0; j < 4; ++j)
        p4[j] = __builtin_elementwise_fma(J[j][k], xv, p4[j]);  // v_pk_fma_f32
    }
    float p[4];
#pragma unroll
    for (int j = 0; j < 4; ++j)
      p[j] = (p4[j].x + p4[j].y) + (p4[j].z + p4[j].w);

    // ---- wave allreduce, same pairing order as p += __shfl_xor(p, m) for
    // m = 32,16,8,4,2,1 (bit-identical), with DPP/swizzle for low latency.
#pragma unroll
    for (int j = 0; j < 4; ++j) {
      p[j] += __shfl_xor(p[j], 32, 64);     // xor32 (ds_permute/permlane)
      p[j] = xadd_swz<0x401F>(p[j]);        // xor16 (ds_swizzle)
      p[j] = xadd_dpp<0x128>(p[j]);         // xor8  (DPP row_ror:8)
      p[j] = xadd_swz<0x101F>(p[j]);        // xor4  (ds_swizzle)
      p[j] = xadd_dpp<0x4E>(p[j]);          // xor2  (DPP quad_perm [2,3,0,1])
      p[j] = xadd_dpp<0xB1>(p[j]);          // xor1  (DPP quad_perm [1,0,3,2])
    }

    const float ic[4] = {icur4.x, icur4.y, icur4.z, icur4.w};
#pragma unroll
    for (int j = 0; j < 4; ++j)
      h[j] = fmaf(COEF, p[j] + ic[j] - h[j], h[j]);

    // ---- publish x(t+1) = relu(h), sign-encoded: this IS the barrier.
    if (t + 1 < TT) {
      const bool encN = (((t + 1) >> 1) & 1) != 0;
      if (l == 0) {
        i32x4 e;
        e.x = __builtin_bit_cast(int, fmaxf(h[0], 0.f));
        e.y = __builtin_bit_cast(int, fmaxf(h[1], 0.f));
        e.z = __builtin_bit_cast(int, fmaxf(h[2], 0.f));
        e.w = __builtin_bit_cast(int, fmaxf(h[3], 0.f));
        if (encN) e |= 0x80000000; else e &= 0x7fffffff;
        store_wt(xbuf + ((t + 1) & 1) * NN + rb, fc(e));
      }
    }
    // trace store: plain cached store (acked during the next poll; off path)
    if (l == 0) {
      f32x4 hv; hv.x = h[0]; hv.y = h[1]; hv.z = h[2]; hv.w = h[3];
      *(f32x4*)(out_h + (size_t)t * NN + rb) = hv;
    }
  }
}

__global__ __launch_bounds__(256)
void readout(const float* __restrict__ h_all,
             const float* __restrict__ ro_w,
             const float* __restrict__ ro_b,
             float* __restrict__ y)
{
  __shared__ float red[4];
  const int t   = blockIdx.x;
  const int tid = threadIdx.x;
  const float* h = h_all + (size_t)t * NN;
  const int base = tid * 8;

  const float4 a0 = *(const float4*)(h + base);
  const float4 a1 = *(const float4*)(h + base + 4);
  const float4 w0 = *(const float4*)(ro_w + base);
  const float4 w1 = *(const float4*)(ro_w + base + 4);

  float s = a0.x * w0.x + a0.y * w0.y + a0.z * w0.z + a0.w * w0.w
          + a1.x * w1.x + a1.y * w1.y + a1.z * w1.z + a1.w * w1.w;
#pragma unroll
  for (int m = 32; m >= 1; m >>= 1) s += __shfl_xor(s, m, 64);

  if ((tid & 63) == 0) red[tid >> 6] = s;
  __syncthreads();
  if (tid == 0) y[t] = red[0] + red[1] + red[2] + red[3] + ro_b[0];
}

extern "C" void kernel_launch(void* const* d_in, const int* in_sizes, int n_in,
                              void* d_out, int out_size, void* d_ws, size_t ws_size,
                              hipStream_t stream)
{
  const float* I_t  = (const float*)d_in[0];
  const float* h0   = (const float*)d_in[1];
  const float* W    = (const float*)d_in[2];
  const float* u    = (const float*)d_in[3];
  const float* v    = (const float*)d_in[4];
  const float* ro_w = (const float*)d_in[5];
  const float* ro_b = (const float*)d_in[6];

  float* y    = (float*)d_out;             // [TT]
  float* outh = (float*)d_out + TT;        // [TT][NN]

  float* xbuf = (float*)d_ws;              // 2*NN floats

  init_xbufs<<<NN / TPB, TPB, 0, stream>>>(xbuf);
  rnn_persist<<<NBLK, TPB, 0, stream>>>(I_t, h0, W, u, v, outh, xbuf);
  readout<<<TT, 256, 0, stream>>>(outh, ro_w, ro_b, y);
}

// Round 11
// 16549.754 us; speedup vs baseline: 1.0709x; 1.0709x over previous
//
#include <hip/hip_runtime.h>
#include <cstdint>
#include <cstddef>

// LowRankRNN: h_{t+1} = h + coef*(-h + J@relu(h) + I_t),  J = G*W - B/N + M u v^T
//
// Persistent kernel, 64 blocks x 512 threads (1 block/CU), J in registers.
// Sync: sign-bit-encoded data IS the flag (x = relu(h) >= 0; x(t) stored with
// sign bit forced to phase enc(t)=(t>>1)&1; decode = clear sign bit; two
// buffers alternate by t&1 so stale data never satisfies a poll).
// Wave w polls only its chunk w (1 dwordx4/lane), decodes into LDS, barrier,
// all waves read x from LDS (R4/R8 structure — the 16.7ms baseline).
//
// R11 = R8 byte-for-byte + ONE change: LGKM-ONLY BARRIER.
//   __syncthreads() compiles to "s_waitcnt vmcnt(0) lgkmcnt(0); s_barrier".
//   The LDS handoff here (poll-register -> ds_write -> barrier -> ds_read)
//   needs only lgkmcnt(0); the vmcnt(0) forced every wave to fully drain its
//   just-issued I_t HBM prefetch (~900cy fresh) and store-acks BEFORE its
//   barrier arrival, every step. Replaced with one asm block
//   "s_waitcnt lgkmcnt(0); s_barrier" ("memory" clobber: ds_writes ordered
//   before, ds_reads after). The I_t prefetch / publish-ack / trace-ack now
//   retire lazily under the NEXT poll's vmcnt(0), where they are ~800-1000cy
//   old (I_t ~ retired) or cheaper than the poll's own round trip (acks).
//   R10's counted-vmcnt staggered poll is ABANDONED (GPU hang: counted waits
//   are unsafe when compiler-authored vmem ops share the window).
//
// Overwrite safety unchanged: publishing x(t+2) requires having acquired all
// of x(t+1), which required every block's step-t barrier, i.e. all step-t
// reads of buffer t&1 are done before anyone can write it again. Per-dword
// store atomicity + per-word sign check handle partial arrival.

constexpr int   NN   = 2048;
constexpr int   TT   = 8192;
constexpr float COEF = 0.001f;             // DT/TAU
constexpr float G_   = 2.0f;
constexpr float BOFF = 10.0f / 2048.0f;    // B/N
constexpr float M_   = 1.5f;

constexpr int NBLK = 64;    // 1 block/CU
constexpr int TPB  = 512;   // 8 waves
constexpr int WPB  = TPB / 64;

typedef float f32x4 __attribute__((ext_vector_type(4)));
typedef int   i32x4 __attribute__((ext_vector_type(4)));

__device__ __forceinline__ i32x4 bc(const f32x4 x) { return __builtin_bit_cast(i32x4, x); }
__device__ __forceinline__ f32x4 fc(const i32x4 x) { return __builtin_bit_cast(f32x4, x); }

// buf0 polled first at t=2 expecting sign-SET  -> init sign-clear (waits)
// buf1 polled first at t=1 expecting sign-CLEAR -> init sign-set  (waits)
__global__ void init_xbufs(float* xb) {
  const int i = blockIdx.x * blockDim.x + threadIdx.x;   // 0..NN-1 over grid
  xb[i]      = 0.0f;
  xb[NN + i] = -1.0f;
}

// One DEVICE-scope 16B load + waitcnt inside one asm block (consumers are
// ordered by register dataflow; rule-#18 safe).
__device__ __forceinline__ f32x4 poll1(const float* p) {
  f32x4 c;
  asm volatile("global_load_dwordx4 %0, %1, off sc1\n\t"
               "s_waitcnt vmcnt(0)"
               : "=&v"(c) : "v"(p) : "memory");
  return c;
}

// DEVICE-scope write-through 16B publish store (visible at the device
// coherence point; per-dword atomicity)
__device__ __forceinline__ void store_wt(float* p, f32x4 v) {
  asm volatile("global_store_dwordx4 %0, %1, off sc1"
               :: "v"(p), "v"(v) : "memory");
}

// LDS-only barrier: orders ds_write (before) / ds_read (after) across the
// block WITHOUT the vmcnt(0) drain __syncthreads would impose. Producer
// write-completion (lgkmcnt(0)) enforced before s_barrier; "memory" clobber
// pins all LDS accesses to the correct side.
__device__ __forceinline__ void lds_barrier() {
  asm volatile("s_waitcnt lgkmcnt(0)\n\t"
               "s_barrier" ::: "memory");
}

// butterfly helpers — value-identical to p += __shfl_xor(p, m)
template <int CTRL>
__device__ __forceinline__ float xadd_dpp(float v) {
  const int t = __builtin_amdgcn_update_dpp(0, __builtin_bit_cast(int, v),
                                            CTRL, 0xF, 0xF, false);
  return v + __builtin_bit_cast(float, t);
}
template <int PAT>
__device__ __forceinline__ float xadd_swz(float v) {
  const int t = __builtin_amdgcn_ds_swizzle(__builtin_bit_cast(int, v), PAT);
  return v + __builtin_bit_cast(float, t);
}

__global__ __launch_bounds__(TPB, 2)
void rnn_persist(const float* __restrict__ I_t,
                 const float* __restrict__ h0,
                 const float* __restrict__ W,
                 const float* __restrict__ u,
                 const float* __restrict__ v,
                 float* __restrict__ out_h,   // d_out + TT, [TT][NN]
                 float* __restrict__ xbuf)    // 2*NN floats
{
  __shared__ f32x4 xs[2][NN / 4];             // 16 KB, double-buffered x

  const int tid = threadIdx.x;
  const int l   = tid & 63;
  const int w   = tid >> 6;
  const int gw  = blockIdx.x * WPB + w;           // global wave 0..511
  const int rb  = gw * 4;                         // this wave's 4 rows
  const int cb  = l * 4;                          // column base per 256-chunk

  // ---- J rows rb..rb+3: J[j][k] <-> row rb+j, cols k*256 + 4l
  f32x4 J[4][8];
#pragma unroll
  for (int j = 0; j < 4; ++j) {
    const float mu = M_ * u[rb + j];
#pragma unroll
    for (int k = 0; k < 8; ++k) {
      const int c = k * 256 + cb;
      const f32x4 wv = *(const f32x4*)(W + (size_t)(rb + j) * NN + c);
      const f32x4 vv = *(const f32x4*)(v + c);
      J[j][k] = G_ * wv - BOFF + mu * vv;
    }
  }

  float h[4];
#pragma unroll
  for (int j = 0; j < 4; ++j) h[j] = h0[rb + j];

  const f32x4 zero4 = {0.f, 0.f, 0.f, 0.f};

  // I_t pipeline: parity-selected regs, issued ~1 step ahead of use
  f32x4 iva = *(const f32x4*)(I_t + rb);              // row 0
  f32x4 ivb = *(const f32x4*)(I_t + (size_t)NN + rb); // row 1 (in flight)

  for (int t = 0; t < TT; ++t) {
    const f32x4 icur4 = (t & 1) ? ivb : iva;
    const int bsel = t & 1;

    // ---- acquire this wave's chunk w of x(t)
    f32x4 c;
    if (t == 0) {
      const f32x4 hv = *(const f32x4*)(h0 + w * 256 + cb);
      c = __builtin_elementwise_max(hv, zero4);   // x(0) = relu(h0)
    } else {
      const bool enc = ((t >> 1) & 1) != 0;       // x(t) stored sign-flipped?
      const float* pb = xbuf + bsel * NN + w * 256 + cb;
      unsigned spins = 0;
      if (enc) {
        for (;;) {  // fresh values have sign SET: all 4 words negative
          c = poll1(pb);
          const i32x4 b = bc(c);
          if (__all(((b.x & b.y) & (b.z & b.w)) < 0)) break;
          if (++spins > (1u << 22)) break;        // escape hatch; never hit
        }
      } else {
        for (;;) {  // fresh values have sign CLEAR: all 4 words non-negative
          c = poll1(pb);
          const i32x4 b = bc(c);
          if (__all(((b.x | b.y) | (b.z | b.w)) >= 0)) break;
          if (++spins > (1u << 22)) break;
        }
      }
      i32x4 b = bc(c);
      b &= 0x7fffffff;                            // exact decode: clear sign
      c = __builtin_bit_cast(f32x4, b);
    }

    // ---- issue I_t row t+2 now (R4 position). With the lgkm-only barrier
    // it is never force-drained; by the next poll's vmcnt(0) it is ~1 full
    // step old and retires for free.
    if (t + 2 < TT) {
      const f32x4 nv = *(const f32x4*)(I_t + (size_t)(t + 2) * NN + rb);
      if (t & 1) ivb = nv; else iva = nv;
    }

    xs[bsel][w * 64 + l] = c;                     // ds_write_b128
    lds_barrier();   // lgkmcnt(0) + s_barrier — NO vmcnt drain

    // ---- p = J @ x from LDS (values already relu'd + decoded)
    f32x4 p4[4] = {zero4, zero4, zero4, zero4};
#pragma unroll
    for (int k = 0; k < 8; ++k) {
      const f32x4 xv = xs[bsel][k * 64 + l];      // ds_read_b128, conflict-free
#pragma unroll
      for (int j = 0; j < 4; ++j)
        p4[j] = __builtin_elementwise_fma(J[j][k], xv, p4[j]);  // v_pk_fma_f32
    }
    float p[4];
#pragma unroll
    for (int j = 0; j < 4; ++j)
      p[j] = (p4[j].x + p4[j].y) + (p4[j].z + p4[j].w);

    // ---- wave allreduce, same pairing order as p += __shfl_xor(p, m) for
    // m = 32,16,8,4,2,1 (bit-identical), with DPP/swizzle for low latency.
#pragma unroll
    for (int j = 0; j < 4; ++j) {
      p[j] += __shfl_xor(p[j], 32, 64);     // xor32 (ds_permute/permlane)
      p[j] = xadd_swz<0x401F>(p[j]);        // xor16 (ds_swizzle)
      p[j] = xadd_dpp<0x128>(p[j]);         // xor8  (DPP row_ror:8)
      p[j] = xadd_swz<0x101F>(p[j]);        // xor4  (ds_swizzle)
      p[j] = xadd_dpp<0x4E>(p[j]);          // xor2  (DPP quad_perm [2,3,0,1])
      p[j] = xadd_dpp<0xB1>(p[j]);          // xor1  (DPP quad_perm [1,0,3,2])
    }

    const float ic[4] = {icur4.x, icur4.y, icur4.z, icur4.w};
#pragma unroll
    for (int j = 0; j < 4; ++j)
      h[j] = fmaf(COEF, p[j] + ic[j] - h[j], h[j]);

    // ---- publish x(t+1) = relu(h), sign-encoded: this IS the barrier.
    if (t + 1 < TT) {
      const bool encN = (((t + 1) >> 1) & 1) != 0;
      if (l == 0) {
        i32x4 e;
        e.x = __builtin_bit_cast(int, fmaxf(h[0], 0.f));
        e.y = __builtin_bit_cast(int, fmaxf(h[1], 0.f));
        e.z = __builtin_bit_cast(int, fmaxf(h[2], 0.f));
        e.w = __builtin_bit_cast(int, fmaxf(h[3], 0.f));
        if (encN) e |= 0x80000000; else e &= 0x7fffffff;
        store_wt(xbuf + ((t + 1) & 1) * NN + rb, fc(e));
      }
    }
    // trace store: plain cached store (ack retires under the next poll)
    if (l == 0) {
      f32x4 hv; hv.x = h[0]; hv.y = h[1]; hv.z = h[2]; hv.w = h[3];
      *(f32x4*)(out_h + (size_t)t * NN + rb) = hv;
    }
  }
}

__global__ __launch_bounds__(256)
void readout(const float* __restrict__ h_all,
             const float* __restrict__ ro_w,
             const float* __restrict__ ro_b,
             float* __restrict__ y)
{
  __shared__ float red[4];
  const int t   = blockIdx.x;
  const int tid = threadIdx.x;
  const float* h = h_all + (size_t)t * NN;
  const int base = tid * 8;

  const float4 a0 = *(const float4*)(h + base);
  const float4 a1 = *(const float4*)(h + base + 4);
  const float4 w0 = *(const float4*)(ro_w + base);
  const float4 w1 = *(const float4*)(ro_w + base + 4);

  float s = a0.x * w0.x + a0.y * w0.y + a0.z * w0.z + a0.w * w0.w
          + a1.x * w1.x + a1.y * w1.y + a1.z * w1.z + a1.w * w1.w;
#pragma unroll
  for (int m = 32; m >= 1; m >>= 1) s += __shfl_xor(s, m, 64);

  if ((tid & 63) == 0) red[tid >> 6] = s;
  __syncthreads();
  if (tid == 0) y[t] = red[0] + red[1] + red[2] + red[3] + ro_b[0];
}

extern "C" void kernel_launch(void* const* d_in, const int* in_sizes, int n_in,
                              void* d_out, int out_size, void* d_ws, size_t ws_size,
                              hipStream_t stream)
{
  const float* I_t  = (const float*)d_in[0];
  const float* h0   = (const float*)d_in[1];
  const float* W    = (const float*)d_in[2];
  const float* u    = (const float*)d_in[3];
  const float* v    = (const float*)d_in[4];
  const float* ro_w = (const float*)d_in[5];
  const float* ro_b = (const float*)d_in[6];

  float* y    = (float*)d_out;             // [TT]
  float* outh = (float*)d_out + TT;        // [TT][NN]

  float* xbuf = (float*)d_ws;              // 2*NN floats

  init_xbufs<<<NN / TPB, TPB, 0, stream>>>(xbuf);
  rnn_persist<<<NBLK, TPB, 0, stream>>>(I_t, h0, W, u, v, outh, xbuf);
  readout<<<TT, 256, 0, stream>>>(outh, ro_w, ro_b, y);
}